// Round 2
// baseline (1451.495 us; speedup 1.0000x reference)
//
#include <hip/hip_runtime.h>

#define PP 64      // context positions (softmax dim)
#define KD 128     // feature dim
#define KC 32      // sigma k-chunk rows per stage
#define SROW 132   // padded LDS row stride for shifted (132%32=4 -> 2-way max alias)

// One block per m. Computes t = S * Sigma (64x128 @ 128x128), then
// score[p] = -dot(t[p], S[p]), then softmax over p.
__global__ __launch_bounds__(256, 2)
void quadform_softmax(const float* __restrict__ color,
                      const float* __restrict__ mew,
                      const float* __restrict__ sigma,
                      float* __restrict__ out) {
  __shared__ __align__(16) float s_lds[PP * SROW];      // 33792 B shifted
  __shared__ __align__(16) float sig_lds[2][KC * KD];   // 32768 B sigma double-buffer
  __shared__ __align__(16) float mew_lds[KD];
  __shared__ float scores_lds[PP];

  const int m = blockIdx.x;
  const int tid = threadIdx.x;

  const float4* c4 = reinterpret_cast<const float4*>(color + (size_t)m * (PP * KD));
  const float4* g4 = reinterpret_cast<const float4*>(sigma + (size_t)m * (KD * KD));

  // ---- stage 0: issue global loads early ----
  float4 creg[8];
#pragma unroll
  for (int i = 0; i < 8; ++i) creg[i] = c4[i * 256 + tid];
  float4 sreg[4];
#pragma unroll
  for (int i = 0; i < 4; ++i) sreg[i] = g4[i * 256 + tid];
  if (tid < 32) {
    reinterpret_cast<float4*>(mew_lds)[tid] =
        reinterpret_cast<const float4*>(mew + (size_t)m * KD)[tid];
  }
  __syncthreads();  // mew ready

  // shifted = color - mew -> LDS (padded rows)
#pragma unroll
  for (int i = 0; i < 8; ++i) {
    int flat = i * 1024 + tid * 4;  // element index in 64x128
    int p = flat >> 7;
    int k = flat & 127;
    float4 mv = *reinterpret_cast<const float4*>(&mew_lds[k]);
    float4 v = creg[i];
    v.x -= mv.x; v.y -= mv.y; v.z -= mv.z; v.w -= mv.w;
    *reinterpret_cast<float4*>(&s_lds[p * SROW + k]) = v;
  }
  // sigma chunk 0 -> buffer 0
#pragma unroll
  for (int i = 0; i < 4; ++i)
    *reinterpret_cast<float4*>(&sig_lds[0][i * 1024 + tid * 4]) = sreg[i];
  __syncthreads();

  // ---- main GEMM: thread tile 4 p-rows x 8 l-cols (l = tx*4..+3 and tx*4+64..+3) ----
  const int ty = tid >> 4;   // 0..15
  const int tx = tid & 15;   // 0..15
  const int p0 = ty * 4;
  const int l0 = tx * 4;

  float acc[4][8];
#pragma unroll
  for (int i = 0; i < 4; ++i)
#pragma unroll
    for (int j = 0; j < 8; ++j) acc[i][j] = 0.f;

  for (int c = 0; c < 4; ++c) {
    float4 nreg[4];
    if (c < 3) {
#pragma unroll
      for (int i = 0; i < 4; ++i) nreg[i] = g4[(c + 1) * 1024 + i * 256 + tid];
    }
    const float* sb = sig_lds[c & 1];
    const int kbase = c * KC;
#pragma unroll
    for (int kk = 0; kk < KC; kk += 4) {
      float4 a[4];
#pragma unroll
      for (int i = 0; i < 4; ++i)
        a[i] = *reinterpret_cast<const float4*>(&s_lds[(p0 + i) * SROW + kbase + kk]);
      float4 blo[4], bhi[4];
#pragma unroll
      for (int d = 0; d < 4; ++d) {
        blo[d] = *reinterpret_cast<const float4*>(&sb[(kk + d) * KD + l0]);
        bhi[d] = *reinterpret_cast<const float4*>(&sb[(kk + d) * KD + l0 + 64]);
      }
#pragma unroll
      for (int i = 0; i < 4; ++i) {
        const float av[4] = {a[i].x, a[i].y, a[i].z, a[i].w};
#pragma unroll
        for (int d = 0; d < 4; ++d) {
          acc[i][0] = fmaf(av[d], blo[d].x, acc[i][0]);
          acc[i][1] = fmaf(av[d], blo[d].y, acc[i][1]);
          acc[i][2] = fmaf(av[d], blo[d].z, acc[i][2]);
          acc[i][3] = fmaf(av[d], blo[d].w, acc[i][3]);
          acc[i][4] = fmaf(av[d], bhi[d].x, acc[i][4]);
          acc[i][5] = fmaf(av[d], bhi[d].y, acc[i][5]);
          acc[i][6] = fmaf(av[d], bhi[d].z, acc[i][6]);
          acc[i][7] = fmaf(av[d], bhi[d].w, acc[i][7]);
        }
      }
    }
    __syncthreads();  // all reads of buf[c&1] complete
    if (c < 3) {
#pragma unroll
      for (int i = 0; i < 4; ++i)
        *reinterpret_cast<float4*>(&sig_lds[(c + 1) & 1][i * 1024 + tid * 4]) = nreg[i];
      __syncthreads();  // buf[(c+1)&1] ready
    }
  }

  // ---- epilogue: score[p] = -sum_l t[p,l]*s[p,l] ----
  float part[4];
#pragma unroll
  for (int i = 0; i < 4; ++i) {
    float4 sv0 = *reinterpret_cast<const float4*>(&s_lds[(p0 + i) * SROW + l0]);
    float4 sv1 = *reinterpret_cast<const float4*>(&s_lds[(p0 + i) * SROW + l0 + 64]);
    part[i] = acc[i][0] * sv0.x + acc[i][1] * sv0.y + acc[i][2] * sv0.z + acc[i][3] * sv0.w
            + acc[i][4] * sv1.x + acc[i][5] * sv1.y + acc[i][6] * sv1.z + acc[i][7] * sv1.w;
  }
  // reduce across the 16 tx-lanes sharing each p (contiguous lanes within a wave)
#pragma unroll
  for (int off = 1; off < 16; off <<= 1) {
#pragma unroll
    for (int i = 0; i < 4; ++i) part[i] += __shfl_xor(part[i], off, 64);
  }
  if (tx == 0) {
#pragma unroll
    for (int i = 0; i < 4; ++i) scores_lds[p0 + i] = -part[i];
  }
  __syncthreads();

  // ---- softmax over the 64 scores (single wave) ----
  if (tid < 64) {
    float sc = scores_lds[tid];
    float mx = sc;
#pragma unroll
    for (int off = 1; off < 64; off <<= 1) mx = fmaxf(mx, __shfl_xor(mx, off, 64));
    float e = __expf(sc - mx);
    float s = e;
#pragma unroll
    for (int off = 1; off < 64; off <<= 1) s += __shfl_xor(s, off, 64);
    out[(size_t)m * PP + tid] = e / s;
  }
}

extern "C" void kernel_launch(void* const* d_in, const int* in_sizes, int n_in,
                              void* d_out, int out_size, void* d_ws, size_t ws_size,
                              hipStream_t stream) {
  const float* color = (const float*)d_in[0];   // (M,64,128) fp32
  const float* mew   = (const float*)d_in[1];   // (M,128)    fp32
  const float* sigma = (const float*)d_in[2];   // (M,128,128) fp32
  float* out = (float*)d_out;                   // (M,64) fp32
  const int M = in_sizes[1] / KD;
  quadform_softmax<<<M, 256, 0, stream>>>(color, mew, sigma, out);
}